// Round 8
// baseline (386.397 us; speedup 1.0000x reference)
//
#include <hip/hip_runtime.h>

typedef unsigned short u16;
typedef unsigned int u32;

#define SPA 2744        // 14*14*14 tokens
#define CH  768
#define NH  12
#define DH  64
#define BB  2
#define TC  2304        // 3*CH
#define MTOT (BB*SPA)   // 5488

typedef __bf16 bf16x8_t __attribute__((ext_vector_type(8)));
typedef __bf16 bf16x4_t __attribute__((ext_vector_type(4)));
typedef short  s16x4    __attribute__((ext_vector_type(4)));
typedef float  f32x4_t  __attribute__((ext_vector_type(4)));

static __device__ __forceinline__ u16 f2bf(float f) {
    union { float f; u32 u; } v; v.f = f;
    u32 u = v.u;
    u += 0x7fffu + ((u >> 16) & 1u);   // RNE
    return (u16)(u >> 16);
}
static __device__ __forceinline__ float bf2f(u16 h) {
    union { u32 u; float f; } v; v.u = ((u32)h) << 16;
    return v.f;
}

// async global->LDS, 16B per lane. LDS dest = wave-uniform base + lane*16.
static __device__ __forceinline__ void gld16(const u16* g, u16* l) {
    __builtin_amdgcn_global_load_lds(
        (const __attribute__((address_space(1))) u32*)(size_t)g,
        (__attribute__((address_space(3))) u32*)(u32)(size_t)l, 16, 0, 0);
}

// ---------------- fp32 -> bf16 weight conversion (both weight mats, 1 launch) ----
__global__ __launch_bounds__(256) void cvt2_kernel(const float* __restrict__ a,
                                                   u16* __restrict__ oa, int n4a,
                                                   const float* __restrict__ bsrc,
                                                   u16* __restrict__ ob, int n4b) {
    int i = blockIdx.x * 256 + threadIdx.x;
    const float* src; u16* dst; int idx;
    if (i < n4a) { src = a; dst = oa; idx = i; }
    else { idx = i - n4a; if (idx >= n4b) return; src = bsrc; dst = ob; }
    float4 f = ((const float4*)src)[idx];
    uint2 o;
    o.x = (u32)f2bf(f.x) | ((u32)f2bf(f.y) << 16);
    o.y = (u32)f2bf(f.z) | ((u32)f2bf(f.w) << 16);
    ((uint2*)dst)[idx] = o;
}

// ---------------- LayerNorm, coalesced: block = 64 tokens ----------------
__global__ __launch_bounds__(256) void ln_kernel(const float* __restrict__ x,
                                                 const float* __restrict__ w,
                                                 const float* __restrict__ bta,
                                                 u16* __restrict__ tn) {
    __shared__ float sred[4][64];
    __shared__ float qred[4][64];
    __shared__ u16 T[32][66];          // [c_local][token], stride 66 -> 2-way (free)
    int tid = threadIdx.x;
    int t = tid & 63, wvi = tid >> 6;
    int g = blockIdx.x * 64 + t;
    int gl = (g < MTOT) ? g : (MTOT - 1);
    int b = gl / SPA, n = gl - b * SPA;
    const float* base = x + (size_t)b * CH * SPA + n;

    float s = 0.f, qa = 0.f;
    for (int c = wvi; c < CH; c += 4) {
        float v = base[(size_t)c * SPA];
        s += v; qa += v * v;
    }
    sred[wvi][t] = s; qred[wvi][t] = qa;
    __syncthreads();
    s  = sred[0][t] + sred[1][t] + sred[2][t] + sred[3][t];
    qa = qred[0][t] + qred[1][t] + qred[2][t] + qred[3][t];
    float mean = s * (1.0f / CH);
    float rstd = rsqrtf(qa * (1.0f / CH) - mean * mean + 1e-5f);

    int tt = tid >> 2, cq = tid & 3;
    int g2 = blockIdx.x * 64 + tt;
    for (int cc = 0; cc < CH; cc += 32) {
        __syncthreads();
#pragma unroll
        for (int j = 0; j < 8; j++) {
            int cl = wvi + 4 * j;                  // wave-uniform channel
            int c = cc + cl;
            float v = base[(size_t)c * SPA];       // coalesced over tokens
            float nv = (v - mean) * rstd * w[c] + bta[c];
            T[cl][t] = f2bf(nv);
        }
        __syncthreads();
        if (g2 < MTOT) {
            union { u16 h[8]; int4 v4; } pk;
#pragma unroll
            for (int e = 0; e < 8; e++) pk.h[e] = T[cq * 8 + e][tt];
            *(int4*)(tn + (size_t)g2 * CH + cc + cq * 8) = pk.v4;
        }
    }
}

// ---------------- bf16 GEMM, C[m][n] = sum_k A[m][k]*Bw[n][k] ----------------
// MODE 0: scatter epilogue -> q/k/v [b][h][n][d], q pre-scaled by dh^-0.5*log2e.
// MODE 1: fused out-proj epilogue: out[b][c][n] = acc + bias[c] + x[b][c][n].
template<int MODE>
__global__ __launch_bounds__(256, 3) void gemm_bt(const u16* __restrict__ A,
                                                  const u16* __restrict__ Bw,
                                                  u16* __restrict__ out0,
                                                  u16* __restrict__ out1,
                                                  u16* __restrict__ out2,
                                                  const float* __restrict__ xres,
                                                  const float* __restrict__ ob,
                                                  float* __restrict__ fout,
                                                  int M, int K) {
    __shared__ __align__(16) u16 As[128 * 32];
    __shared__ __align__(16) u16 Bs[128 * 32];
    int tid = threadIdx.x;
    int m0 = blockIdx.y * 128;
    int n0 = blockIdx.x * 128;
    int wv = tid >> 6, lane = tid & 63;
    int wm = (wv >> 1) * 64, wn = (wv & 1) * 64;
    int quad = lane >> 4, l16 = lane & 15;

    f32x4_t zero = {0.f, 0.f, 0.f, 0.f};
    f32x4_t acc[4][4];
#pragma unroll
    for (int i = 0; i < 4; i++)
#pragma unroll
        for (int j = 0; j < 4; j++) acc[i][j] = zero;

    int rl = lane >> 2, pos = lane & 3;
    int sw = (l16 >> 1) & 3;
    for (int k0 = 0; k0 < K; k0 += 32) {
        __syncthreads();
#pragma unroll
        for (int p = 0; p < 2; p++) {
            int rbase = p * 64 + wv * 16;
            int row = rbase + rl;
            int gch = pos ^ ((row >> 1) & 3);
            int gm = m0 + row; if (gm >= M) gm = M - 1;
            gld16(A + (size_t)gm * K + k0 + gch * 8, As + rbase * 32);
            gld16(Bw + (size_t)(n0 + row) * K + k0 + gch * 8, Bs + rbase * 32);
        }
        __syncthreads();
        bf16x8_t af[4], bfr[4];
#pragma unroll
        for (int i = 0; i < 4; i++)
            af[i] = *(const bf16x8_t*)(As + (wm + i * 16 + l16) * 32 + ((quad ^ sw) * 8));
#pragma unroll
        for (int j = 0; j < 4; j++)
            bfr[j] = *(const bf16x8_t*)(Bs + (wn + j * 16 + l16) * 32 + ((quad ^ sw) * 8));
#pragma unroll
        for (int i = 0; i < 4; i++)
#pragma unroll
            for (int j = 0; j < 4; j++)
                acc[i][j] = __builtin_amdgcn_mfma_f32_16x16x32_bf16(af[i], bfr[j], acc[i][j], 0, 0, 0);
    }

    if (MODE == 0) {
        int which = n0 / CH;                  // block-uniform (CH % 128 == 0)
        int rb = n0 - which * CH;
        u16* base = (which == 0) ? out0 : ((which == 1) ? out1 : out2);
        float qs = (which == 0) ? 0.18033688011112042f : 1.0f;  // dh^-0.5*log2(e)
#pragma unroll
        for (int i = 0; i < 4; i++)
#pragma unroll
            for (int r = 0; r < 4; r++) {
                int gm = m0 + wm + i * 16 + quad * 4 + r;
                if (gm < M) {
                    int b = gm / SPA, n = gm - b * SPA;
#pragma unroll
                    for (int j = 0; j < 4; j++) {
                        int rem = rb + wn + j * 16 + l16;
                        int h = rem >> 6, d = rem & 63;
                        base[((size_t)(b * NH + h) * SPA + n) * DH + d] = f2bf(acc[i][j][r] * qs);
                    }
                }
            }
    } else {
        // fused: lane holds 4 consecutive tokens (quad*4+r) for channel gn
#pragma unroll
        for (int i = 0; i < 4; i++) {
            int gm0 = m0 + wm + i * 16 + quad * 4;
            if (gm0 < M) {                    // groups of 4, M%4==0 -> all-or-none
                int b = gm0 / SPA;            // SPA%4==0 -> no b straddle
                int n = gm0 - b * SPA;
#pragma unroll
                for (int j = 0; j < 4; j++) {
                    int gn = n0 + wn + j * 16 + l16;
                    size_t xo = ((size_t)(b * CH + gn)) * SPA + n;
                    float4 xv = *(const float4*)(xres + xo);
                    float bias = ob[gn];
                    float4 rr;
                    rr.x = xv.x + bias + acc[i][j][0];
                    rr.y = xv.y + bias + acc[i][j][1];
                    rr.z = xv.z + bias + acc[i][j][2];
                    rr.w = xv.w + bias + acc[i][j][3];
                    *(float4*)(fout + xo) = rr;
                }
            }
        }
    }
}

// ---------------- V transpose: [bh][n][d] -> [bh][d][n] ----------------
__global__ __launch_bounds__(256) void vtrans_kernel(const u16* __restrict__ v,
                                                     u16* __restrict__ vt) {
    __shared__ __align__(16) u16 T[64 * 72];
    int bh = blockIdx.y;
    int n0 = blockIdx.x * 64;
    int tid = threadIdx.x;
#pragma unroll
    for (int h = 0; h < 2; h++) {
        int chunk = tid + h * 256;
        int r = chunk >> 3, cs = chunk & 7;
        int n = n0 + r;
        int4 val = make_int4(0, 0, 0, 0);
        if (n < SPA) val = *(const int4*)(v + ((size_t)bh * SPA + n) * DH + cs * 8);
        *(int4*)(T + r * 72 + cs * 8) = val;
    }
    __syncthreads();
#pragma unroll
    for (int h = 0; h < 2; h++) {
        int chunk = tid + h * 256;
        int d = chunk >> 3, cs = chunk & 7;
        int nb = n0 + cs * 8;
        if (nb < SPA) {
            union { u16 s[8]; int4 v4; } tmp;
#pragma unroll
            for (int e = 0; e < 8; e++) tmp.s[e] = T[(cs * 8 + e) * 72 + d];
            *(int4*)(vt + ((size_t)bh * DH + d) * SPA + nb) = tmp.v4;
        }
    }
}

// ---------------- flash attention v8 ----------------
// Round-7 lesson: every wave reads the FULL K+V tile from LDS as fragments,
// so LDS-read bytes/q scale as 1/(q-per-wave) -> LDS-BW-bound. Fix here:
//  - K fragments in REGISTERS, loaded direct from global (L2-resident),
//    double-buffered via STATIC even/odd register sets (kA/kB; round-3's
//    spill came from a dynamic buffer index — avoided by 2x loop unroll).
//  - V stays in LDS (padded 72), double-buffered, 1 barrier/iter.
//  - 128 q / block, 4 waves x 32 q-cols; p = exp2(s) (Q pre-scaled);
//    l via ones-A MFMA.
template<bool PRE, bool MASK>
static __device__ __forceinline__ void attn_iter(
    int kt, const u16* kg, const u16* vg,
    const u16* Vcur, u16* Vnxt,
    bf16x8_t (&kc)[2][4], bf16x8_t (&kn)[2][4],
    const bf16x8_t (&bq)[2][2],
    f32x4_t (&o)[2][4], f32x4_t (&lacc)[2],
    s16x4 ones, int quad, int l16, int vd, int vj) {
    __syncthreads();                     // V stage for tile kt complete
    int4 vpre0, vpre1;
    if (PRE) {
        int kv0n = (kt + 1) * 64;
        // prefetch next K tile into registers (16B/lane, 64B row segments)
#pragma unroll
        for (int i = 0; i < 4; i++) {
            int kr = kv0n + i * 16 + l16; if (kr >= SPA) kr = SPA - 1;
            const u16* p = kg + (size_t)kr * DH + quad * 8;
            kn[0][i] = *(const bf16x8_t*)(p);
            kn[1][i] = *(const bf16x8_t*)(p + 32);
        }
        int kvs0 = kv0n + vj * 8;     if (kvs0 > SPA - 8) kvs0 = SPA - 8;
        int kvs1 = kv0n + vj * 8 + 8; if (kvs1 > SPA - 8) kvs1 = SPA - 8;
        vpre0 = *(const int4*)(vg + (size_t)vd * SPA + kvs0);
        vpre1 = *(const int4*)(vg + (size_t)vd * SPA + kvs1);
    }

    // ---- QK: S^T tiles from register K frags ----
    f32x4_t zero = {0.f, 0.f, 0.f, 0.f};
    f32x4_t s[2][4];
#pragma unroll
    for (int qf = 0; qf < 2; qf++)
#pragma unroll
        for (int i = 0; i < 4; i++) s[qf][i] = zero;
#pragma unroll
    for (int ks = 0; ks < 2; ks++)
#pragma unroll
        for (int i = 0; i < 4; i++) {
            s[0][i] = __builtin_amdgcn_mfma_f32_16x16x32_bf16(kc[ks][i], bq[0][ks], s[0][i], 0, 0, 0);
            s[1][i] = __builtin_amdgcn_mfma_f32_16x16x32_bf16(kc[ks][i], bq[1][ks], s[1][i], 0, 0, 0);
        }

    // park next V tile into the other LDS buffer
    if (PRE) {
        *(int4*)(Vnxt + vd * 72 + vj * 8) = vpre0;
        *(int4*)(Vnxt + vd * 72 + vj * 8 + 8) = vpre1;
    }

    // ---- one-pass softmax: p = exp2(s) ----
    s16x4 bp[2][4];
#pragma unroll
    for (int qf = 0; qf < 2; qf++)
#pragma unroll
        for (int i = 0; i < 4; i++) {
            bf16x4_t pb;
#pragma unroll
            for (int r = 0; r < 4; r++) {
                float p = __builtin_amdgcn_exp2f(s[qf][i][r]);
                if (MASK) {
                    if (kt * 64 + i * 16 + quad * 4 + r >= SPA) p = 0.f;
                }
                pb[r] = (__bf16)p;
            }
            union { bf16x4_t b; s16x4 s; } u; u.b = pb;
            bp[qf][i] = u.s;
        }

    // ---- l += ones · P ; O^T += V^T-frag · P-frag ----
#pragma unroll
    for (int c = 0; c < 4; c++) {
        lacc[0] = __builtin_amdgcn_mfma_f32_16x16x16bf16_1k(ones, bp[0][c], lacc[0], 0, 0, 0);
        lacc[1] = __builtin_amdgcn_mfma_f32_16x16x16bf16_1k(ones, bp[1][c], lacc[1], 0, 0, 0);
#pragma unroll
        for (int i = 0; i < 4; i++) {
            s16x4 av = *(const s16x4*)(Vcur + (i * 16 + l16) * 72 + (c * 4 + quad) * 4);
            o[0][i] = __builtin_amdgcn_mfma_f32_16x16x16bf16_1k(av, bp[0][c], o[0][i], 0, 0, 0);
            o[1][i] = __builtin_amdgcn_mfma_f32_16x16x16bf16_1k(av, bp[1][c], o[1][i], 0, 0, 0);
        }
    }
}

__global__ __launch_bounds__(256, 2) void attn_kernel(const u16* __restrict__ q,
                                                      const u16* __restrict__ k,
                                                      const u16* __restrict__ vt,
                                                      u16* __restrict__ out) {
    __shared__ __align__(16) u16 Vbuf[2][64 * 72];   // [d][kv_local] padded
    int qg = blockIdx.x, h = blockIdx.y, b = blockIdx.z;
    int bh = b * NH + h;
    int tid = threadIdx.x;
    int wv = tid >> 6, lane = tid & 63;
    int quad = lane >> 4, l16 = lane & 15;
    int q0w = qg * 128 + wv * 32;

    const u16* qgp = q + (size_t)bh * SPA * DH;
    const u16* kg = k + (size_t)bh * SPA * DH;
    const u16* vg = vt + (size_t)bh * DH * SPA;

    // Q B-frags: lane holds Q[q = col][d = ks*32 + quad*8 .. +8]
    bf16x8_t bq[2][2];
    int qglob[2];
#pragma unroll
    for (int qf = 0; qf < 2; qf++) {
        int qq = q0w + qf * 16 + l16;
        qglob[qf] = qq;
        int qld = (qq < SPA) ? qq : (SPA - 1);
#pragma unroll
        for (int ks = 0; ks < 2; ks++)
            bq[qf][ks] = *(const bf16x8_t*)(qgp + (size_t)qld * DH + ks * 32 + quad * 8);
    }

    f32x4_t zero = {0.f, 0.f, 0.f, 0.f};
    f32x4_t o[2][4];
#pragma unroll
    for (int qf = 0; qf < 2; qf++)
#pragma unroll
        for (int i = 0; i < 4; i++) o[qf][i] = zero;
    f32x4_t lacc[2];
    lacc[0] = zero; lacc[1] = zero;
    s16x4 ones;
    ones[0] = ones[1] = ones[2] = ones[3] = (short)0x3F80;  // bf16 1.0 x4

    int vd = tid >> 2, vj = (tid & 3) * 2;

    // ---- prologue: K tile 0 -> kA (registers); V tile 0 -> Vbuf[0] ----
    bf16x8_t kA[2][4], kB[2][4];
#pragma unroll
    for (int i = 0; i < 4; i++) {
        const u16* p = kg + (size_t)(i * 16 + l16) * DH + quad * 8;
        kA[0][i] = *(const bf16x8_t*)(p);
        kA[1][i] = *(const bf16x8_t*)(p + 32);
    }
    *(int4*)(Vbuf[0] + vd * 72 + vj * 8) = *(const int4*)(vg + (size_t)vd * SPA + vj * 8);
    *(int4*)(Vbuf[0] + vd * 72 + vj * 8 + 8) = *(const int4*)(vg + (size_t)vd * SPA + vj * 8 + 8);

#pragma unroll 1
    for (int kt2 = 0; kt2 < 21; kt2++) {
        attn_iter<true, false>(kt2 * 2, kg, vg, Vbuf[0], Vbuf[1],
                               kA, kB, bq, o, lacc, ones, quad, l16, vd, vj);
        attn_iter<true, false>(kt2 * 2 + 1, kg, vg, Vbuf[1], Vbuf[0],
                               kB, kA, bq, o, lacc, ones, quad, l16, vd, vj);
    }
    attn_iter<false, true>(42, kg, vg, Vbuf[0], Vbuf[1],
                           kA, kB, bq, o, lacc, ones, quad, l16, vd, vj);

    // ---- epilogue: l = lacc[qf][0] (all rows equal), normalize, store O^T ----
#pragma unroll
    for (int qf = 0; qf < 2; qf++) {
        int qq = qglob[qf];
        if (qq < SPA) {
            float inv = 1.0f / lacc[qf][0];
            u16* op = out + ((size_t)(b * SPA + qq)) * CH + h * DH;
#pragma unroll
            for (int i = 0; i < 4; i++) {
                bf16x4_t ov;
#pragma unroll
                for (int r = 0; r < 4; r++) ov[r] = (__bf16)(o[qf][i][r] * inv);
                *(bf16x4_t*)(op + i * 16 + quad * 4) = ov;
            }
        }
    }
}

extern "C" void kernel_launch(void* const* d_in, const int* in_sizes, int n_in,
                              void* d_out, int out_size, void* d_ws, size_t ws_size,
                              hipStream_t stream) {
    const float* x      = (const float*)d_in[0];
    const float* norm_w = (const float*)d_in[1];
    const float* norm_b = (const float*)d_in[2];
    const float* qkv_w  = (const float*)d_in[3];
    const float* out_w  = (const float*)d_in[4];
    const float* out_b  = (const float*)d_in[5];
    float* out = (float*)d_out;

    char* ws = (char*)d_ws;
    size_t off = 0;
    auto alloc = [&](size_t bytes) -> void* {
        void* p = ws + off;
        off += (bytes + 255) & ~(size_t)255;
        return p;
    };
    u16* tn      = (u16*)alloc((size_t)MTOT * CH * 2);
    u16* qkvw_bf = (u16*)alloc((size_t)TC * CH * 2);
    u16* outw_bf = (u16*)alloc((size_t)CH * CH * 2);
    u16* qb      = (u16*)alloc((size_t)BB * NH * SPA * DH * 2);
    u16* kb      = (u16*)alloc((size_t)BB * NH * SPA * DH * 2);
    u16* vb      = (u16*)alloc((size_t)BB * NH * SPA * DH * 2);
    u16* vtb     = (u16*)alloc((size_t)BB * NH * SPA * DH * 2);
    u16* ao      = (u16*)alloc((size_t)MTOT * CH * 2);

    int n4a = TC * CH / 4, n4b = CH * CH / 4;
    cvt2_kernel<<<(n4a + n4b + 255) / 256, 256, 0, stream>>>(qkv_w, qkvw_bf, n4a, out_w, outw_bf, n4b);
    ln_kernel<<<(MTOT + 63) / 64, 256, 0, stream>>>(x, norm_w, norm_b, tn);
    gemm_bt<0><<<dim3(TC / 128, (MTOT + 127) / 128), 256, 0, stream>>>(
        tn, qkvw_bf, qb, kb, vb, nullptr, nullptr, nullptr, MTOT, CH);
    vtrans_kernel<<<dim3((SPA + 63) / 64, BB * NH), 256, 0, stream>>>(vb, vtb);
    attn_kernel<<<dim3((SPA + 127) / 128, NH, BB), 256, 0, stream>>>(qb, kb, vtb, ao);
    gemm_bt<1><<<dim3(CH / 128, (MTOT + 127) / 128), 256, 0, stream>>>(
        ao, outw_bf, nullptr, nullptr, nullptr, x, out_b, out, MTOT, CH);
}

// Round 9
// 298.117 us; speedup vs baseline: 1.2961x; 1.2961x over previous
//
#include <hip/hip_runtime.h>

typedef unsigned short u16;
typedef unsigned int u32;

#define SPA 2744        // 14*14*14 tokens
#define CH  768
#define NH  12
#define DH  64
#define BB  2
#define TC  2304        // 3*CH
#define MTOT (BB*SPA)   // 5488

typedef __bf16 bf16x8_t __attribute__((ext_vector_type(8)));
typedef __bf16 bf16x4_t __attribute__((ext_vector_type(4)));
typedef short  s16x4    __attribute__((ext_vector_type(4)));
typedef float  f32x4_t  __attribute__((ext_vector_type(4)));

static __device__ __forceinline__ u16 f2bf(float f) {
    union { float f; u32 u; } v; v.f = f;
    u32 u = v.u;
    u += 0x7fffu + ((u >> 16) & 1u);   // RNE
    return (u16)(u >> 16);
}
static __device__ __forceinline__ float bf2f(u16 h) {
    union { u32 u; float f; } v; v.u = ((u32)h) << 16;
    return v.f;
}

// async global->LDS, 16B per lane. LDS dest = wave-uniform base + lane*16.
static __device__ __forceinline__ void gld16(const u16* g, u16* l) {
    __builtin_amdgcn_global_load_lds(
        (const __attribute__((address_space(1))) u32*)(size_t)g,
        (__attribute__((address_space(3))) u32*)(u32)(size_t)l, 16, 0, 0);
}

// ---------------- fp32 -> bf16 weight conversion (both weight mats, 1 launch) ----
__global__ __launch_bounds__(256) void cvt2_kernel(const float* __restrict__ a,
                                                   u16* __restrict__ oa, int n4a,
                                                   const float* __restrict__ bsrc,
                                                   u16* __restrict__ ob, int n4b) {
    int i = blockIdx.x * 256 + threadIdx.x;
    const float* src; u16* dst; int idx;
    if (i < n4a) { src = a; dst = oa; idx = i; }
    else { idx = i - n4a; if (idx >= n4b) return; src = bsrc; dst = ob; }
    float4 f = ((const float4*)src)[idx];
    uint2 o;
    o.x = (u32)f2bf(f.x) | ((u32)f2bf(f.y) << 16);
    o.y = (u32)f2bf(f.z) | ((u32)f2bf(f.w) << 16);
    ((uint2*)dst)[idx] = o;
}

// ---------------- LayerNorm, coalesced: block = 64 tokens ----------------
__global__ __launch_bounds__(256) void ln_kernel(const float* __restrict__ x,
                                                 const float* __restrict__ w,
                                                 const float* __restrict__ bta,
                                                 u16* __restrict__ tn) {
    __shared__ float sred[4][64];
    __shared__ float qred[4][64];
    __shared__ u16 T[32][66];          // [c_local][token], stride 66 -> 2-way (free)
    int tid = threadIdx.x;
    int t = tid & 63, wvi = tid >> 6;
    int g = blockIdx.x * 64 + t;
    int gl = (g < MTOT) ? g : (MTOT - 1);
    int b = gl / SPA, n = gl - b * SPA;
    const float* base = x + (size_t)b * CH * SPA + n;

    float s = 0.f, qa = 0.f;
    for (int c = wvi; c < CH; c += 4) {
        float v = base[(size_t)c * SPA];
        s += v; qa += v * v;
    }
    sred[wvi][t] = s; qred[wvi][t] = qa;
    __syncthreads();
    s  = sred[0][t] + sred[1][t] + sred[2][t] + sred[3][t];
    qa = qred[0][t] + qred[1][t] + qred[2][t] + qred[3][t];
    float mean = s * (1.0f / CH);
    float rstd = rsqrtf(qa * (1.0f / CH) - mean * mean + 1e-5f);

    int tt = tid >> 2, cq = tid & 3;
    int g2 = blockIdx.x * 64 + tt;
    for (int cc = 0; cc < CH; cc += 32) {
        __syncthreads();
#pragma unroll
        for (int j = 0; j < 8; j++) {
            int cl = wvi + 4 * j;                  // wave-uniform channel
            int c = cc + cl;
            float v = base[(size_t)c * SPA];       // coalesced over tokens
            float nv = (v - mean) * rstd * w[c] + bta[c];
            T[cl][t] = f2bf(nv);
        }
        __syncthreads();
        if (g2 < MTOT) {
            union { u16 h[8]; int4 v4; } pk;
#pragma unroll
            for (int e = 0; e < 8; e++) pk.h[e] = T[cq * 8 + e][tt];
            *(int4*)(tn + (size_t)g2 * CH + cc + cq * 8) = pk.v4;
        }
    }
}

// ---------------- bf16 GEMM, C[m][n] = sum_k A[m][k]*Bw[n][k] ----------------
// MODE 0: scatter epilogue -> q/k/v [b][h][n][d], q pre-scaled by dh^-0.5*log2e.
// MODE 1: fused out-proj epilogue: out[b][c][n] = acc + bias[c] + x[b][c][n].
template<int MODE>
__global__ __launch_bounds__(256, 3) void gemm_bt(const u16* __restrict__ A,
                                                  const u16* __restrict__ Bw,
                                                  u16* __restrict__ out0,
                                                  u16* __restrict__ out1,
                                                  u16* __restrict__ out2,
                                                  const float* __restrict__ xres,
                                                  const float* __restrict__ ob,
                                                  float* __restrict__ fout,
                                                  int M, int K) {
    __shared__ __align__(16) u16 As[128 * 32];
    __shared__ __align__(16) u16 Bs[128 * 32];
    int tid = threadIdx.x;
    int m0 = blockIdx.y * 128;
    int n0 = blockIdx.x * 128;
    int wv = tid >> 6, lane = tid & 63;
    int wm = (wv >> 1) * 64, wn = (wv & 1) * 64;
    int quad = lane >> 4, l16 = lane & 15;

    f32x4_t zero = {0.f, 0.f, 0.f, 0.f};
    f32x4_t acc[4][4];
#pragma unroll
    for (int i = 0; i < 4; i++)
#pragma unroll
        for (int j = 0; j < 4; j++) acc[i][j] = zero;

    int rl = lane >> 2, pos = lane & 3;
    int sw = (l16 >> 1) & 3;
    for (int k0 = 0; k0 < K; k0 += 32) {
        __syncthreads();
#pragma unroll
        for (int p = 0; p < 2; p++) {
            int rbase = p * 64 + wv * 16;
            int row = rbase + rl;
            int gch = pos ^ ((row >> 1) & 3);
            int gm = m0 + row; if (gm >= M) gm = M - 1;
            gld16(A + (size_t)gm * K + k0 + gch * 8, As + rbase * 32);
            gld16(Bw + (size_t)(n0 + row) * K + k0 + gch * 8, Bs + rbase * 32);
        }
        __syncthreads();
        bf16x8_t af[4], bfr[4];
#pragma unroll
        for (int i = 0; i < 4; i++)
            af[i] = *(const bf16x8_t*)(As + (wm + i * 16 + l16) * 32 + ((quad ^ sw) * 8));
#pragma unroll
        for (int j = 0; j < 4; j++)
            bfr[j] = *(const bf16x8_t*)(Bs + (wn + j * 16 + l16) * 32 + ((quad ^ sw) * 8));
#pragma unroll
        for (int i = 0; i < 4; i++)
#pragma unroll
            for (int j = 0; j < 4; j++)
                acc[i][j] = __builtin_amdgcn_mfma_f32_16x16x32_bf16(af[i], bfr[j], acc[i][j], 0, 0, 0);
    }

    if (MODE == 0) {
        int which = n0 / CH;                  // block-uniform (CH % 128 == 0)
        int rb = n0 - which * CH;
        u16* base = (which == 0) ? out0 : ((which == 1) ? out1 : out2);
        float qs = (which == 0) ? 0.18033688011112042f : 1.0f;  // dh^-0.5*log2(e)
#pragma unroll
        for (int i = 0; i < 4; i++)
#pragma unroll
            for (int r = 0; r < 4; r++) {
                int gm = m0 + wm + i * 16 + quad * 4 + r;
                if (gm < M) {
                    int b = gm / SPA, n = gm - b * SPA;
#pragma unroll
                    for (int j = 0; j < 4; j++) {
                        int rem = rb + wn + j * 16 + l16;
                        int h = rem >> 6, d = rem & 63;
                        base[((size_t)(b * NH + h) * SPA + n) * DH + d] = f2bf(acc[i][j][r] * qs);
                    }
                }
            }
    } else {
        // fused: lane holds 4 consecutive tokens (quad*4+r) for channel gn
#pragma unroll
        for (int i = 0; i < 4; i++) {
            int gm0 = m0 + wm + i * 16 + quad * 4;
            if (gm0 < M) {                    // groups of 4, M%4==0 -> all-or-none
                int b = gm0 / SPA;            // SPA%4==0 -> no b straddle
                int n = gm0 - b * SPA;
#pragma unroll
                for (int j = 0; j < 4; j++) {
                    int gn = n0 + wn + j * 16 + l16;
                    size_t xo = ((size_t)(b * CH + gn)) * SPA + n;
                    float4 xv = *(const float4*)(xres + xo);
                    float bias = ob[gn];
                    float4 rr;
                    rr.x = xv.x + bias + acc[i][j][0];
                    rr.y = xv.y + bias + acc[i][j][1];
                    rr.z = xv.z + bias + acc[i][j][2];
                    rr.w = xv.w + bias + acc[i][j][3];
                    *(float4*)(fout + xo) = rr;
                }
            }
        }
    }
}

// ---------------- V transpose: [bh][n][d] -> [bh][d][n] ----------------
__global__ __launch_bounds__(256) void vtrans_kernel(const u16* __restrict__ v,
                                                     u16* __restrict__ vt) {
    __shared__ __align__(16) u16 T[64 * 72];
    int bh = blockIdx.y;
    int n0 = blockIdx.x * 64;
    int tid = threadIdx.x;
#pragma unroll
    for (int h = 0; h < 2; h++) {
        int chunk = tid + h * 256;
        int r = chunk >> 3, cs = chunk & 7;
        int n = n0 + r;
        int4 val = make_int4(0, 0, 0, 0);
        if (n < SPA) val = *(const int4*)(v + ((size_t)bh * SPA + n) * DH + cs * 8);
        *(int4*)(T + r * 72 + cs * 8) = val;
    }
    __syncthreads();
#pragma unroll
    for (int h = 0; h < 2; h++) {
        int chunk = tid + h * 256;
        int d = chunk >> 3, cs = chunk & 7;
        int nb = n0 + cs * 8;
        if (nb < SPA) {
            union { u16 s[8]; int4 v4; } tmp;
#pragma unroll
            for (int e = 0; e < 8; e++) tmp.s[e] = T[(cs * 8 + e) * 72 + d];
            *(int4*)(vt + ((size_t)bh * DH + d) * SPA + nb) = tmp.v4;
        }
    }
}

// ---------------- flash attention v9 = round-6 structure + XCD-aware remap ----
// 128 q / block, 4 waves x 32 q-cols; K LDS (gld16, swizzled), V LDS (padded),
// double-buffered, ONE barrier/iter; p = exp2(s) (Q pre-scaled); l via ones-A
// MFMA. NEW: 1D grid 528, xcd = g&7 owns 3 bh -> the 66 co-resident blocks of
// an XCD touch only ~4.2 MB of K/V (~L2 size) instead of ~17 MB.
__global__ __launch_bounds__(256, 4) void attn_kernel(const u16* __restrict__ q,
                                                      const u16* __restrict__ k,
                                                      const u16* __restrict__ vt,
                                                      u16* __restrict__ out) {
    __shared__ __align__(16) u16 Kbuf[2][64 * 64];   // [kv_local][d] swizzled
    __shared__ __align__(16) u16 Vbuf[2][64 * 72];   // [d][kv_local] padded
    int g = blockIdx.x;                 // 528 = 8 xcd * 3 bh * 22 qtiles
    int xcd = g & 7, slot = g >> 3;     // slot in [0,66)
    int bh = xcd * 3 + slot % 3;
    int qg = slot / 3;                  // [0,22)
    int b = bh / NH, h = bh - b * NH;
    int tid = threadIdx.x;
    int wv = tid >> 6, lane = tid & 63;
    int quad = lane >> 4, l16 = lane & 15;
    int q0w = qg * 128 + wv * 32;

    const u16* qgp = q + (size_t)bh * SPA * DH;
    const u16* kg = k + (size_t)bh * SPA * DH;
    const u16* vg = vt + (size_t)bh * DH * SPA;

    // Q B-frags: lane holds Q[q = col][d = ks*32 + quad*8 .. +8]
    bf16x8_t bq[2][2];
    int qglob[2];
#pragma unroll
    for (int qf = 0; qf < 2; qf++) {
        int qq = q0w + qf * 16 + l16;
        qglob[qf] = qq;
        int qld = (qq < SPA) ? qq : (SPA - 1);
#pragma unroll
        for (int ks = 0; ks < 2; ks++)
            bq[qf][ks] = *(const bf16x8_t*)(qgp + (size_t)qld * DH + ks * 32 + quad * 8);
    }

    f32x4_t zero = {0.f, 0.f, 0.f, 0.f};
    f32x4_t o[2][4];
#pragma unroll
    for (int qf = 0; qf < 2; qf++)
#pragma unroll
        for (int i = 0; i < 4; i++) o[qf][i] = zero;
    f32x4_t lacc[2];
    lacc[0] = zero; lacc[1] = zero;
    s16x4 ones;
    ones[0] = ones[1] = ones[2] = ones[3] = (short)0x3F80;  // bf16 1.0 x4

    int rl8 = lane >> 3, pos8 = lane & 7;
    int sw8 = l16 & 7;
    int vd = tid >> 2, vj = (tid & 3) * 2;

    // ---- prologue: stage tile 0 into buffer 0 ----
#pragma unroll
    for (int p = 0; p < 2; p++) {
        int rbase = p * 32 + wv * 8;
        int row = rbase + rl8;
        int gch = pos8 ^ (row & 7);
        gld16(kg + (size_t)row * DH + gch * 8, Kbuf[0] + rbase * 64);
    }
#pragma unroll
    for (int s2 = 0; s2 < 2; s2++) {
        int j2 = vj + s2;
        int4 val = *(const int4*)(vg + (size_t)vd * SPA + j2 * 8);
        *(int4*)(Vbuf[0] + vd * 72 + j2 * 8) = val;
    }

    for (int kt = 0; kt < 43; kt++) {
        __syncthreads();                         // stage(kt) complete
        int cur = kt & 1, nxt = cur ^ 1;
        int kv0 = kt * 64;
        bool havenext = (kt + 1 < 43);
        int4 vpre[2];
        if (havenext) {
            int kv0n = kv0 + 64;
#pragma unroll
            for (int p = 0; p < 2; p++) {
                int rbase = p * 32 + wv * 8;
                int row = rbase + rl8;
                int gch = pos8 ^ (row & 7);
                int kr = kv0n + row; if (kr >= SPA) kr = SPA - 1;
                gld16(kg + (size_t)kr * DH + gch * 8, Kbuf[nxt] + rbase * 64);
            }
#pragma unroll
            for (int s2 = 0; s2 < 2; s2++) {
                int kvs = kv0n + (vj + s2) * 8; if (kvs > SPA - 8) kvs = SPA - 8;
                vpre[s2] = *(const int4*)(vg + (size_t)vd * SPA + kvs);
            }
        }

        // ---- QK: S^T tiles, kv = kv0 + i*16 + quad*4 + r, q-col = l16 ----
        f32x4_t s[2][4];
#pragma unroll
        for (int qf = 0; qf < 2; qf++)
#pragma unroll
            for (int i = 0; i < 4; i++) s[qf][i] = zero;
#pragma unroll
        for (int ks = 0; ks < 2; ks++) {
            bf16x8_t ak[4];
#pragma unroll
            for (int i = 0; i < 4; i++)
                ak[i] = *(const bf16x8_t*)(Kbuf[cur] + (i * 16 + l16) * 64 + (((ks * 4 + quad) ^ sw8) * 8));
#pragma unroll
            for (int i = 0; i < 4; i++) {
                s[0][i] = __builtin_amdgcn_mfma_f32_16x16x32_bf16(ak[i], bq[0][ks], s[0][i], 0, 0, 0);
                s[1][i] = __builtin_amdgcn_mfma_f32_16x16x32_bf16(ak[i], bq[1][ks], s[1][i], 0, 0, 0);
            }
        }

        // park next V tile in LDS (loads are ~QK-latency old by now)
        if (havenext) {
#pragma unroll
            for (int s2 = 0; s2 < 2; s2++)
                *(int4*)(Vbuf[nxt] + vd * 72 + (vj + s2) * 8) = vpre[s2];
        }

        // ---- one-pass softmax: p = exp2(s); zero pad kv rows on tile 42 ----
        s16x4 bp[2][4];
        if (kt != 42) {
#pragma unroll
            for (int qf = 0; qf < 2; qf++)
#pragma unroll
                for (int i = 0; i < 4; i++) {
                    bf16x4_t pb;
#pragma unroll
                    for (int r = 0; r < 4; r++)
                        pb[r] = (__bf16)__builtin_amdgcn_exp2f(s[qf][i][r]);
                    union { bf16x4_t b; s16x4 s; } u; u.b = pb;
                    bp[qf][i] = u.s;
                }
        } else {
#pragma unroll
            for (int qf = 0; qf < 2; qf++)
#pragma unroll
                for (int i = 0; i < 4; i++) {
                    bf16x4_t pb;
#pragma unroll
                    for (int r = 0; r < 4; r++) {
                        float p = __builtin_amdgcn_exp2f(s[qf][i][r]);
                        if (kv0 + i * 16 + quad * 4 + r >= SPA) p = 0.f;
                        pb[r] = (__bf16)p;
                    }
                    union { bf16x4_t b; s16x4 s; } u; u.b = pb;
                    bp[qf][i] = u.s;
                }
        }

        // ---- l += ones · P ; O^T += V^T-frag · P-frag ----
#pragma unroll
        for (int c = 0; c < 4; c++) {
            lacc[0] = __builtin_amdgcn_mfma_f32_16x16x16bf16_1k(ones, bp[0][c], lacc[0], 0, 0, 0);
            lacc[1] = __builtin_amdgcn_mfma_f32_16x16x16bf16_1k(ones, bp[1][c], lacc[1], 0, 0, 0);
#pragma unroll
            for (int i = 0; i < 4; i++) {
                s16x4 av = *(const s16x4*)(Vbuf[cur] + (i * 16 + l16) * 72 + (c * 4 + quad) * 4);
                o[0][i] = __builtin_amdgcn_mfma_f32_16x16x16bf16_1k(av, bp[0][c], o[0][i], 0, 0, 0);
                o[1][i] = __builtin_amdgcn_mfma_f32_16x16x16bf16_1k(av, bp[1][c], o[1][i], 0, 0, 0);
            }
        }
    }

    // ---- epilogue: l = lacc[qf][0] (all rows equal), normalize, store O^T ----
#pragma unroll
    for (int qf = 0; qf < 2; qf++) {
        int qq = qglob[qf];
        if (qq < SPA) {
            float inv = 1.0f / lacc[qf][0];
            u16* op = out + ((size_t)(b * SPA + qq)) * CH + h * DH;
#pragma unroll
            for (int i = 0; i < 4; i++) {
                bf16x4_t ov;
#pragma unroll
                for (int r = 0; r < 4; r++) ov[r] = (__bf16)(o[qf][i][r] * inv);
                *(bf16x4_t*)(op + i * 16 + quad * 4) = ov;
            }
        }
    }
}

extern "C" void kernel_launch(void* const* d_in, const int* in_sizes, int n_in,
                              void* d_out, int out_size, void* d_ws, size_t ws_size,
                              hipStream_t stream) {
    const float* x      = (const float*)d_in[0];
    const float* norm_w = (const float*)d_in[1];
    const float* norm_b = (const float*)d_in[2];
    const float* qkv_w  = (const float*)d_in[3];
    const float* out_w  = (const float*)d_in[4];
    const float* out_b  = (const float*)d_in[5];
    float* out = (float*)d_out;

    char* ws = (char*)d_ws;
    size_t off = 0;
    auto alloc = [&](size_t bytes) -> void* {
        void* p = ws + off;
        off += (bytes + 255) & ~(size_t)255;
        return p;
    };
    u16* tn      = (u16*)alloc((size_t)MTOT * CH * 2);
    u16* qkvw_bf = (u16*)alloc((size_t)TC * CH * 2);
    u16* outw_bf = (u16*)alloc((size_t)CH * CH * 2);
    u16* qb      = (u16*)alloc((size_t)BB * NH * SPA * DH * 2);
    u16* kb      = (u16*)alloc((size_t)BB * NH * SPA * DH * 2);
    u16* vb      = (u16*)alloc((size_t)BB * NH * SPA * DH * 2);
    u16* vtb     = (u16*)alloc((size_t)BB * NH * SPA * DH * 2);
    u16* ao      = (u16*)alloc((size_t)MTOT * CH * 2);

    int n4a = TC * CH / 4, n4b = CH * CH / 4;
    cvt2_kernel<<<(n4a + n4b + 255) / 256, 256, 0, stream>>>(qkv_w, qkvw_bf, n4a, out_w, outw_bf, n4b);
    ln_kernel<<<(MTOT + 63) / 64, 256, 0, stream>>>(x, norm_w, norm_b, tn);
    gemm_bt<0><<<dim3(TC / 128, (MTOT + 127) / 128), 256, 0, stream>>>(
        tn, qkvw_bf, qb, kb, vb, nullptr, nullptr, nullptr, MTOT, CH);
    vtrans_kernel<<<dim3((SPA + 63) / 64, BB * NH), 256, 0, stream>>>(vb, vtb);
    attn_kernel<<<528, 256, 0, stream>>>(qb, kb, vtb, ao);
    gemm_bt<1><<<dim3(CH / 128, (MTOT + 127) / 128), 256, 0, stream>>>(
        ao, outw_bf, nullptr, nullptr, nullptr, x, out_b, out, MTOT, CH);
}

// Round 10
// 258.060 us; speedup vs baseline: 1.4973x; 1.1552x over previous
//
#include <hip/hip_runtime.h>

typedef unsigned short u16;
typedef unsigned int u32;

#define SPA 2744        // 14*14*14 tokens
#define CH  768
#define NH  12
#define DH  64
#define BB  2
#define TC  2304        // 3*CH
#define MTOT (BB*SPA)   // 5488
#define CVTB 2304       // cvt blocks fused ahead of ln blocks

typedef __bf16 bf16x8_t __attribute__((ext_vector_type(8)));
typedef __bf16 bf16x4_t __attribute__((ext_vector_type(4)));
typedef short  s16x4    __attribute__((ext_vector_type(4)));
typedef float  f32x4_t  __attribute__((ext_vector_type(4)));

static __device__ __forceinline__ u16 f2bf(float f) {
    union { float f; u32 u; } v; v.f = f;
    u32 u = v.u;
    u += 0x7fffu + ((u >> 16) & 1u);   // RNE
    return (u16)(u >> 16);
}

// async global->LDS, 16B per lane. LDS dest = wave-uniform base + lane*16.
static __device__ __forceinline__ void gld16(const u16* g, u16* l) {
    __builtin_amdgcn_global_load_lds(
        (const __attribute__((address_space(1))) u32*)(size_t)g,
        (__attribute__((address_space(3))) u32*)(u32)(size_t)l, 16, 0, 0);
}

// ---------------- fused: weight cvt (blocks < CVTB) + LayerNorm (rest) ----------
// LN: block = 64 tokens, float4-over-token loads (16B/lane), two-pass,
// shuffle+LDS reduction, b64 LDS transpose for int4 tn writes.
__global__ __launch_bounds__(256) void cvtln_kernel(const float* __restrict__ qkv_w,
                                                    u16* __restrict__ qkvw_bf, int n4a,
                                                    const float* __restrict__ out_w,
                                                    u16* __restrict__ outw_bf,
                                                    const float* __restrict__ x,
                                                    const float* __restrict__ w,
                                                    const float* __restrict__ bta,
                                                    u16* __restrict__ tn) {
    int tid = threadIdx.x;
    if (blockIdx.x < CVTB) {
        int i = blockIdx.x * 256 + tid;           // covers n4a + n4b exactly
        const float* src; u16* dst; int idx;
        if (i < n4a) { src = qkv_w; dst = qkvw_bf; idx = i; }
        else { src = out_w; dst = outw_bf; idx = i - n4a; }
        float4 f = ((const float4*)src)[idx];
        uint2 o;
        o.x = (u32)f2bf(f.x) | ((u32)f2bf(f.y) << 16);
        o.y = (u32)f2bf(f.z) | ((u32)f2bf(f.w) << 16);
        ((uint2*)dst)[idx] = o;
        return;
    }
    int bid = blockIdx.x - CVTB;                  // [0,86)
    __shared__ f32x4_t redS[4][16];
    __shared__ f32x4_t redQ[4][16];
    __shared__ u16 T[32][68];                     // [ch_local][token]
    int grp = tid & 15, chl = tid >> 4;           // chl in [0,16)
    int wvi = tid >> 6, l16g = tid & 15;
    (void)l16g;
    int tok0 = bid * 64 + grp * 4;
    int gb = (tok0 + 3 < MTOT) ? tok0 : (MTOT - 4);
    int b = gb / SPA, n = gb - b * SPA;           // groups of 4 never straddle b
    const float* base = x + (size_t)b * CH * SPA + n;

    f32x4_t s4 = {0.f, 0.f, 0.f, 0.f}, q4 = {0.f, 0.f, 0.f, 0.f};
    for (int c0 = 0; c0 < CH; c0 += 16) {
        float4 v = *(const float4*)(base + (size_t)(c0 + chl) * SPA);
        s4[0] += v.x; s4[1] += v.y; s4[2] += v.z; s4[3] += v.w;
        q4[0] += v.x * v.x; q4[1] += v.y * v.y; q4[2] += v.z * v.z; q4[3] += v.w * v.w;
    }
#pragma unroll
    for (int m = 16; m <= 32; m <<= 1)
#pragma unroll
        for (int e = 0; e < 4; e++) {
            s4[e] += __shfl_xor(s4[e], m);
            q4[e] += __shfl_xor(q4[e], m);
        }
    if ((tid & 63) < 16) { redS[wvi][grp] = s4; redQ[wvi][grp] = q4; }
    __syncthreads();
    f32x4_t st = redS[0][grp], qt = redQ[0][grp];
#pragma unroll
    for (int wv2 = 1; wv2 < 4; wv2++) {
        f32x4_t a = redS[wv2][grp], c = redQ[wv2][grp];
#pragma unroll
        for (int e = 0; e < 4; e++) { st[e] += a[e]; qt[e] += c[e]; }
    }
    f32x4_t mean4, rstd4;
#pragma unroll
    for (int e = 0; e < 4; e++) {
        mean4[e] = st[e] * (1.0f / CH);
        rstd4[e] = rsqrtf(qt[e] * (1.0f / CH) - mean4[e] * mean4[e] + 1e-5f);
    }

    int tokl = tid >> 2, qq = tid & 3;
    int g2 = bid * 64 + tokl;
    for (int c0 = 0; c0 < CH; c0 += 32) {
        __syncthreads();
#pragma unroll
        for (int h = 0; h < 2; h++) {
            int cc = c0 + h * 16 + chl;
            float4 v = *(const float4*)(base + (size_t)cc * SPA);
            float ws = w[cc], bs = bta[cc];
            union { u16 h4[4]; } pk;
            pk.h4[0] = f2bf((v.x - mean4[0]) * rstd4[0] * ws + bs);
            pk.h4[1] = f2bf((v.y - mean4[1]) * rstd4[1] * ws + bs);
            pk.h4[2] = f2bf((v.z - mean4[2]) * rstd4[2] * ws + bs);
            pk.h4[3] = f2bf((v.w - mean4[3]) * rstd4[3] * ws + bs);
            *(uint2*)(&T[h * 16 + chl][grp * 4]) = *(uint2*)pk.h4;
        }
        __syncthreads();
        if (g2 < MTOT) {
            union { u16 h[8]; int4 v4; } pk;
#pragma unroll
            for (int e = 0; e < 8; e++) pk.h[e] = T[qq * 8 + e][tokl];
            *(int4*)(tn + (size_t)g2 * CH + c0 + qq * 8) = pk.v4;
        }
    }
}

// ---------------- QKV GEMM: C[m][n] = tn[m][k]*W[n][k], scatter epilogue ----------
__global__ __launch_bounds__(256, 3) void gemm_qkv(const u16* __restrict__ A,
                                                   const u16* __restrict__ Bw,
                                                   u16* __restrict__ out0,
                                                   u16* __restrict__ out1,
                                                   u16* __restrict__ out2) {
    const int M = MTOT, K = CH;
    __shared__ __align__(16) u16 As[128 * 32];
    __shared__ __align__(16) u16 Bs[128 * 32];
    int tid = threadIdx.x;
    int m0 = blockIdx.y * 128;
    int n0 = blockIdx.x * 128;
    int wv = tid >> 6, lane = tid & 63;
    int wm = (wv >> 1) * 64, wn = (wv & 1) * 64;
    int quad = lane >> 4, l16 = lane & 15;

    f32x4_t zero = {0.f, 0.f, 0.f, 0.f};
    f32x4_t acc[4][4];
#pragma unroll
    for (int i = 0; i < 4; i++)
#pragma unroll
        for (int j = 0; j < 4; j++) acc[i][j] = zero;

    int rl = lane >> 2, pos = lane & 3;
    int sw = (l16 >> 1) & 3;
    for (int k0 = 0; k0 < K; k0 += 32) {
        __syncthreads();
#pragma unroll
        for (int p = 0; p < 2; p++) {
            int rbase = p * 64 + wv * 16;
            int row = rbase + rl;
            int gch = pos ^ ((row >> 1) & 3);
            int gm = m0 + row; if (gm >= M) gm = M - 1;
            gld16(A + (size_t)gm * K + k0 + gch * 8, As + rbase * 32);
            gld16(Bw + (size_t)(n0 + row) * K + k0 + gch * 8, Bs + rbase * 32);
        }
        __syncthreads();
        bf16x8_t af[4], bfr[4];
#pragma unroll
        for (int i = 0; i < 4; i++)
            af[i] = *(const bf16x8_t*)(As + (wm + i * 16 + l16) * 32 + ((quad ^ sw) * 8));
#pragma unroll
        for (int j = 0; j < 4; j++)
            bfr[j] = *(const bf16x8_t*)(Bs + (wn + j * 16 + l16) * 32 + ((quad ^ sw) * 8));
#pragma unroll
        for (int i = 0; i < 4; i++)
#pragma unroll
            for (int j = 0; j < 4; j++)
                acc[i][j] = __builtin_amdgcn_mfma_f32_16x16x32_bf16(af[i], bfr[j], acc[i][j], 0, 0, 0);
    }

    int which = n0 / CH;                  // block-uniform (CH % 128 == 0)
    int rb = n0 - which * CH;
    u16* base = (which == 0) ? out0 : ((which == 1) ? out1 : out2);
    float qs = (which == 0) ? 0.18033688011112042f : 1.0f;  // dh^-0.5*log2(e)
#pragma unroll
    for (int i = 0; i < 4; i++)
#pragma unroll
        for (int r = 0; r < 4; r++) {
            int gm = m0 + wm + i * 16 + quad * 4 + r;
            if (gm < M) {
                int b = gm / SPA, n = gm - b * SPA;
#pragma unroll
                for (int j = 0; j < 4; j++) {
                    int rem = rb + wn + j * 16 + l16;
                    int h = rem >> 6, d = rem & 63;
                    base[((size_t)(b * NH + h) * SPA + n) * DH + d] = f2bf(acc[i][j][r] * qs);
                }
            }
        }
}

// ---------------- out-proj GEMM, 128x64 tiles, fused bias+residual epilogue ----
__global__ __launch_bounds__(256, 4) void gemm_out(const u16* __restrict__ A,
                                                   const u16* __restrict__ Bw,
                                                   const float* __restrict__ xres,
                                                   const float* __restrict__ ob,
                                                   float* __restrict__ fout) {
    const int M = MTOT, K = CH;
    __shared__ __align__(16) u16 As[128 * 32];
    __shared__ __align__(16) u16 Bs[64 * 32];
    int tid = threadIdx.x;
    int m0 = blockIdx.y * 128;
    int n0 = blockIdx.x * 64;
    int wv = tid >> 6, lane = tid & 63;
    int wm = (wv >> 1) * 64, wn = (wv & 1) * 32;
    int quad = lane >> 4, l16 = lane & 15;

    f32x4_t zero = {0.f, 0.f, 0.f, 0.f};
    f32x4_t acc[4][2];
#pragma unroll
    for (int i = 0; i < 4; i++)
#pragma unroll
        for (int j = 0; j < 2; j++) acc[i][j] = zero;

    int rl = lane >> 2, pos = lane & 3;
    int sw = (l16 >> 1) & 3;
    for (int k0 = 0; k0 < K; k0 += 32) {
        __syncthreads();
#pragma unroll
        for (int p = 0; p < 2; p++) {
            int rbase = p * 64 + wv * 16;
            int row = rbase + rl;
            int gch = pos ^ ((row >> 1) & 3);
            int gm = m0 + row; if (gm >= M) gm = M - 1;
            gld16(A + (size_t)gm * K + k0 + gch * 8, As + rbase * 32);
        }
        {
            int row = wv * 16 + rl;
            int gch = pos ^ ((row >> 1) & 3);
            gld16(Bw + (size_t)(n0 + row) * K + k0 + gch * 8, Bs + (wv * 16) * 32);
        }
        __syncthreads();
        bf16x8_t af[4], bfr[2];
#pragma unroll
        for (int i = 0; i < 4; i++)
            af[i] = *(const bf16x8_t*)(As + (wm + i * 16 + l16) * 32 + ((quad ^ sw) * 8));
#pragma unroll
        for (int j = 0; j < 2; j++)
            bfr[j] = *(const bf16x8_t*)(Bs + (wn + j * 16 + l16) * 32 + ((quad ^ sw) * 8));
#pragma unroll
        for (int i = 0; i < 4; i++)
#pragma unroll
            for (int j = 0; j < 2; j++)
                acc[i][j] = __builtin_amdgcn_mfma_f32_16x16x32_bf16(af[i], bfr[j], acc[i][j], 0, 0, 0);
    }

    // fused: lane holds 4 consecutive tokens (quad*4+r) for channel gn
#pragma unroll
    for (int i = 0; i < 4; i++) {
        int gm0 = m0 + wm + i * 16 + quad * 4;
        if (gm0 < M) {                    // groups of 4, M%4==0, SPA%4==0
            int b = gm0 / SPA;
            int n = gm0 - b * SPA;
#pragma unroll
            for (int j = 0; j < 2; j++) {
                int gn = n0 + wn + j * 16 + l16;
                size_t xo = ((size_t)(b * CH + gn)) * SPA + n;
                float4 xv = *(const float4*)(xres + xo);
                float bias = ob[gn];
                float4 rr;
                rr.x = xv.x + bias + acc[i][j][0];
                rr.y = xv.y + bias + acc[i][j][1];
                rr.z = xv.z + bias + acc[i][j][2];
                rr.w = xv.w + bias + acc[i][j][3];
                *(float4*)(fout + xo) = rr;
            }
        }
    }
}

// ---------------- V transpose: [bh][n][d] -> [bh][d][n] ----------------
__global__ __launch_bounds__(256) void vtrans_kernel(const u16* __restrict__ v,
                                                     u16* __restrict__ vt) {
    __shared__ __align__(16) u16 T[64 * 72];
    int bh = blockIdx.y;
    int n0 = blockIdx.x * 64;
    int tid = threadIdx.x;
#pragma unroll
    for (int h = 0; h < 2; h++) {
        int chunk = tid + h * 256;
        int r = chunk >> 3, cs = chunk & 7;
        int n = n0 + r;
        int4 val = make_int4(0, 0, 0, 0);
        if (n < SPA) val = *(const int4*)(v + ((size_t)bh * SPA + n) * DH + cs * 8);
        *(int4*)(T + r * 72 + cs * 8) = val;
    }
    __syncthreads();
#pragma unroll
    for (int h = 0; h < 2; h++) {
        int chunk = tid + h * 256;
        int d = chunk >> 3, cs = chunk & 7;
        int nb = n0 + cs * 8;
        if (nb < SPA) {
            union { u16 s[8]; int4 v4; } tmp;
#pragma unroll
            for (int e = 0; e < 8; e++) tmp.s[e] = T[(cs * 8 + e) * 72 + d];
            *(int4*)(vt + ((size_t)bh * DH + d) * SPA + nb) = tmp.v4;
        }
    }
}

// ---------------- flash attention v10: 128-kv super-iters ----------------
// r9 structure (XCD remap, K gld16+swizzle, V padded LDS, exp2-raw, MFMA-l)
// with 128 kv per barrier (22 super-iters vs 43): half the barrier drains,
// 2x MFMA run-length. QK is k-inner per i-tile so score regs are transient.
__global__ __launch_bounds__(256, 2) void attn_kernel(const u16* __restrict__ q,
                                                      const u16* __restrict__ k,
                                                      const u16* __restrict__ vt,
                                                      u16* __restrict__ out) {
    __shared__ __align__(16) u16 Kbuf[2][128 * 64];   // [kv_local][d] swizzled
    __shared__ __align__(16) u16 Vbuf[2][64 * 136];   // [d][kv_local] padded
    int g = blockIdx.x;                 // 528 = 8 xcd * 3 bh * 22 qtiles
    int xcd = g & 7, slot = g >> 3;
    int bh = xcd * 3 + slot % 3;
    int qg = slot / 3;
    int b = bh / NH, h = bh - b * NH;
    int tid = threadIdx.x;
    int wv = tid >> 6, lane = tid & 63;
    int quad = lane >> 4, l16 = lane & 15;
    int q0w = qg * 128 + wv * 32;

    const u16* qgp = q + (size_t)bh * SPA * DH;
    const u16* kg = k + (size_t)bh * SPA * DH;
    const u16* vg = vt + (size_t)bh * DH * SPA;

    bf16x8_t bq[2][2];
    int qglob[2];
#pragma unroll
    for (int qf = 0; qf < 2; qf++) {
        int qq = q0w + qf * 16 + l16;
        qglob[qf] = qq;
        int qld = (qq < SPA) ? qq : (SPA - 1);
#pragma unroll
        for (int ks = 0; ks < 2; ks++)
            bq[qf][ks] = *(const bf16x8_t*)(qgp + (size_t)qld * DH + ks * 32 + quad * 8);
    }

    f32x4_t zero = {0.f, 0.f, 0.f, 0.f};
    f32x4_t o[2][4];
#pragma unroll
    for (int qf = 0; qf < 2; qf++)
#pragma unroll
        for (int i = 0; i < 4; i++) o[qf][i] = zero;
    f32x4_t lacc[2];
    lacc[0] = zero; lacc[1] = zero;
    s16x4 ones;
    ones[0] = ones[1] = ones[2] = ones[3] = (short)0x3F80;  // bf16 1.0 x4

    int rl8 = lane >> 3, pos8 = lane & 7;
    int sw8 = l16 & 7;
    int vd = tid >> 2, vc = (tid & 3) * 32;

    // ---- prologue: stage super-tile 0 ----
#pragma unroll
    for (int p = 0; p < 4; p++) {
        int rbase = p * 32 + wv * 8;
        int row = rbase + rl8;
        int gch = pos8 ^ (row & 7);
        gld16(kg + (size_t)row * DH + gch * 8, Kbuf[0] + rbase * 64);
    }
#pragma unroll
    for (int s2 = 0; s2 < 4; s2++)
        *(int4*)(Vbuf[0] + vd * 136 + vc + s2 * 8) =
            *(const int4*)(vg + (size_t)vd * SPA + vc + s2 * 8);

    for (int si = 0; si < 22; si++) {
        __syncthreads();
        int cur = si & 1, nxt = cur ^ 1;
        int kv0 = si * 128;
        bool hn = (si < 21);
        int4 vp0, vp1, vp2, vp3;
        if (hn) {
            int kb = kv0 + 128;
#pragma unroll
            for (int p = 0; p < 4; p++) {
                int rbase = p * 32 + wv * 8;
                int row = rbase + rl8;
                int gch = pos8 ^ (row & 7);
                int kr = kb + row; if (kr >= SPA) kr = SPA - 1;
                gld16(kg + (size_t)kr * DH + gch * 8, Kbuf[nxt] + rbase * 64);
            }
            int c0 = kb + vc;
            int a0 = c0;      if (a0 > SPA - 8) a0 = SPA - 8;
            int a1 = c0 + 8;  if (a1 > SPA - 8) a1 = SPA - 8;
            int a2 = c0 + 16; if (a2 > SPA - 8) a2 = SPA - 8;
            int a3 = c0 + 24; if (a3 > SPA - 8) a3 = SPA - 8;
            vp0 = *(const int4*)(vg + (size_t)vd * SPA + a0);
            vp1 = *(const int4*)(vg + (size_t)vd * SPA + a1);
            vp2 = *(const int4*)(vg + (size_t)vd * SPA + a2);
            vp3 = *(const int4*)(vg + (size_t)vd * SPA + a3);
        }

        // ---- QK + exp, k-inner per i-tile (scores transient) ----
        s16x4 bp[2][8];
#pragma unroll
        for (int i = 0; i < 8; i++) {
            const u16* krow = Kbuf[cur] + (i * 16 + l16) * 64;
            bf16x8_t ak0 = *(const bf16x8_t*)(krow + ((quad ^ sw8) * 8));
            bf16x8_t ak1 = *(const bf16x8_t*)(krow + (((4 + quad) ^ sw8) * 8));
            f32x4_t s0 = __builtin_amdgcn_mfma_f32_16x16x32_bf16(ak0, bq[0][0], zero, 0, 0, 0);
            s0 = __builtin_amdgcn_mfma_f32_16x16x32_bf16(ak1, bq[0][1], s0, 0, 0, 0);
            f32x4_t s1 = __builtin_amdgcn_mfma_f32_16x16x32_bf16(ak0, bq[1][0], zero, 0, 0, 0);
            s1 = __builtin_amdgcn_mfma_f32_16x16x32_bf16(ak1, bq[1][1], s1, 0, 0, 0);
            bf16x4_t p0, p1;
            if (si != 21) {
#pragma unroll
                for (int r = 0; r < 4; r++) {
                    p0[r] = (__bf16)__builtin_amdgcn_exp2f(s0[r]);
                    p1[r] = (__bf16)__builtin_amdgcn_exp2f(s1[r]);
                }
            } else {
#pragma unroll
                for (int r = 0; r < 4; r++) {
                    float e0 = __builtin_amdgcn_exp2f(s0[r]);
                    float e1 = __builtin_amdgcn_exp2f(s1[r]);
                    bool bad = (kv0 + i * 16 + quad * 4 + r) >= SPA;
                    p0[r] = (__bf16)(bad ? 0.f : e0);
                    p1[r] = (__bf16)(bad ? 0.f : e1);
                }
            }
            union { bf16x4_t b; s16x4 s; } u0, u1;
            u0.b = p0; u1.b = p1;
            bp[0][i] = u0.s; bp[1][i] = u1.s;
        }

        // park next V tile (loads are QK-phase old by now)
        if (hn) {
            *(int4*)(Vbuf[nxt] + vd * 136 + vc)      = vp0;
            *(int4*)(Vbuf[nxt] + vd * 136 + vc + 8)  = vp1;
            *(int4*)(Vbuf[nxt] + vd * 136 + vc + 16) = vp2;
            *(int4*)(Vbuf[nxt] + vd * 136 + vc + 24) = vp3;
        }

        // ---- l += ones·P ; O^T += V^T·P ----
#pragma unroll
        for (int c = 0; c < 8; c++) {
            lacc[0] = __builtin_amdgcn_mfma_f32_16x16x16bf16_1k(ones, bp[0][c], lacc[0], 0, 0, 0);
            lacc[1] = __builtin_amdgcn_mfma_f32_16x16x16bf16_1k(ones, bp[1][c], lacc[1], 0, 0, 0);
#pragma unroll
            for (int i = 0; i < 4; i++) {
                s16x4 av = *(const s16x4*)(Vbuf[cur] + (i * 16 + l16) * 136 + c * 16 + quad * 4);
                o[0][i] = __builtin_amdgcn_mfma_f32_16x16x16bf16_1k(av, bp[0][c], o[0][i], 0, 0, 0);
                o[1][i] = __builtin_amdgcn_mfma_f32_16x16x16bf16_1k(av, bp[1][c], o[1][i], 0, 0, 0);
            }
        }
    }

    // ---- epilogue: l = lacc[qf][0], normalize, store O^T ----
#pragma unroll
    for (int qf = 0; qf < 2; qf++) {
        int qq = qglob[qf];
        if (qq < SPA) {
            float inv = 1.0f / lacc[qf][0];
            u16* op = out + ((size_t)(b * SPA + qq)) * CH + h * DH;
#pragma unroll
            for (int i = 0; i < 4; i++) {
                bf16x4_t ov;
#pragma unroll
                for (int r = 0; r < 4; r++) ov[r] = (__bf16)(o[qf][i][r] * inv);
                *(bf16x4_t*)(op + i * 16 + quad * 4) = ov;
            }
        }
    }
}

extern "C" void kernel_launch(void* const* d_in, const int* in_sizes, int n_in,
                              void* d_out, int out_size, void* d_ws, size_t ws_size,
                              hipStream_t stream) {
    const float* x      = (const float*)d_in[0];
    const float* norm_w = (const float*)d_in[1];
    const float* norm_b = (const float*)d_in[2];
    const float* qkv_w  = (const float*)d_in[3];
    const float* out_w  = (const float*)d_in[4];
    const float* out_b  = (const float*)d_in[5];
    float* out = (float*)d_out;

    char* ws = (char*)d_ws;
    size_t off = 0;
    auto alloc = [&](size_t bytes) -> void* {
        void* p = ws + off;
        off += (bytes + 255) & ~(size_t)255;
        return p;
    };
    u16* tn      = (u16*)alloc((size_t)MTOT * CH * 2);
    u16* qkvw_bf = (u16*)alloc((size_t)TC * CH * 2);
    u16* outw_bf = (u16*)alloc((size_t)CH * CH * 2);
    u16* qb      = (u16*)alloc((size_t)BB * NH * SPA * DH * 2);
    u16* kb      = (u16*)alloc((size_t)BB * NH * SPA * DH * 2);
    u16* vb      = (u16*)alloc((size_t)BB * NH * SPA * DH * 2);
    u16* vtb     = (u16*)alloc((size_t)BB * NH * SPA * DH * 2);
    u16* ao      = (u16*)alloc((size_t)MTOT * CH * 2);

    int n4a = TC * CH / 4;
    cvtln_kernel<<<CVTB + (MTOT + 63) / 64, 256, 0, stream>>>(
        qkv_w, qkvw_bf, n4a, out_w, outw_bf, x, norm_w, norm_b, tn);
    gemm_qkv<<<dim3(TC / 128, (MTOT + 127) / 128), 256, 0, stream>>>(
        tn, qkvw_bf, qb, kb, vb);
    vtrans_kernel<<<dim3((SPA + 63) / 64, BB * NH), 256, 0, stream>>>(vb, vtb);
    attn_kernel<<<528, 256, 0, stream>>>(qb, kb, vtb, ao);
    gemm_out<<<dim3(CH / 64, (MTOT + 127) / 128), 256, 0, stream>>>(
        ao, outw_bf, x, out_b, out);
}